// Round 1
// baseline (2039.217 us; speedup 1.0000x reference)
//
#include <hip/hip_runtime.h>
#include <hip/hip_bf16.h>

#define NVIEW 6
#define NN    6400
#define DD    2048
#define HH    512
#define CC    256
#define EE    204800
#define ZF    768   // C + H

typedef __bf16 bf16x8 __attribute__((ext_vector_type(8)));
typedef float  f32x4  __attribute__((ext_vector_type(4)));

// ---------------------------------------------------------------------------
// CSR build: histogram -> block scan -> scatter
// ---------------------------------------------------------------------------
__global__ void k_hist(const int* __restrict__ dst, int* __restrict__ hist) {
  int e = blockIdx.x * 256 + threadIdx.x;
  int v = blockIdx.y;
  if (e < EE) atomicAdd(&hist[v * NN + dst[(size_t)v * EE + e]], 1);
}

__global__ __launch_bounds__(1024) void k_scan(const int* __restrict__ hist,
                                               int* __restrict__ rp) {
  int v = blockIdx.x;
  const int* h = hist + v * NN;
  int* r = rp + v * (NN + 1);
  __shared__ int part[1024];
  int t = threadIdx.x;
  const int CH = 7;                       // 1024*7 >= 6400
  int base = t * CH;
  int loc[CH];
  int s = 0;
#pragma unroll
  for (int i = 0; i < CH; i++) {
    int idx = base + i;
    int val = (idx < NN) ? h[idx] : 0;
    loc[i] = s;
    s += val;
  }
  part[t] = s;
  __syncthreads();
  for (int off = 1; off < 1024; off <<= 1) {
    int x = (t >= off) ? part[t - off] : 0;
    __syncthreads();
    part[t] += x;
    __syncthreads();
  }
  int pre = (t == 0) ? 0 : part[t - 1];
#pragma unroll
  for (int i = 0; i < CH; i++) {
    int idx = base + i;
    if (idx < NN) r[idx] = pre + loc[i];
  }
  if (t == 1023) r[NN] = part[1023];     // == EE
}

__global__ void k_cursor(const int* __restrict__ rp, int* __restrict__ cur) {
  int i = blockIdx.x * 256 + threadIdx.x;       // 0 .. NVIEW*NN-1
  if (i < NVIEW * NN) {
    int v = i / NN, n = i - v * NN;
    cur[i] = rp[v * (NN + 1) + n];
  }
}

__global__ void k_scatter(const int* __restrict__ src, const int* __restrict__ dstA,
                          const float* __restrict__ val, int* __restrict__ cur,
                          int* __restrict__ ssrc, float* __restrict__ sval) {
  int e = blockIdx.x * 256 + threadIdx.x;
  int v = blockIdx.y;
  if (e < EE) {
    size_t idx = (size_t)v * EE + e;
    int d = dstA[idx];
    int pos = atomicAdd(&cur[v * NN + d], 1);
    ssrc[(size_t)v * EE + pos] = src[idx];
    sval[(size_t)v * EE + pos] = val[idx];
  }
}

// ---------------------------------------------------------------------------
// bf16 MFMA GEMM: C[v] = A[v] (fp32 [M,K]) * W[v or shared] (fp32 [K,Nc])
// 128x128 tile / block, 4 waves, each wave 64x64 (4x4 frags of 16x16x32).
// LDS fragment-contiguous layout: [kgroup(4)][rowgrp(8)*17 pad] of bf16x8.
// ---------------------------------------------------------------------------
__global__ __launch_bounds__(256) void k_gemm(
    const float* __restrict__ A, const float* __restrict__ W,
    float* __restrict__ Cmat, int K, int Nc, int wPerView)
{
  int tid  = threadIdx.x;
  int lane = tid & 63;
  int wid  = tid >> 6;
  int bm = blockIdx.x, bn = blockIdx.y, v = blockIdx.z;

  const float* Av = A + (size_t)v * NN * K;
  const float* Wv = W + (wPerView ? (size_t)v * K * Nc : 0);
  float* Cv = Cmat + (size_t)v * NN * Nc;

  __shared__ bf16x8 Ash[4][136];   // [kgrp][ (row>>4)*17 + (row&15) ]
  __shared__ bf16x8 Bsh[4][136];   // [kgrp][ (col>>4)*17 + (col&15) ], elem j = W[k0+g*8+j][col]
  __bf16* BshS = (__bf16*)&Bsh[0][0];

  f32x4 acc[4][4];
#pragma unroll
  for (int m = 0; m < 4; m++)
#pragma unroll
    for (int n = 0; n < 4; n++) acc[m][n] = (f32x4){0.f, 0.f, 0.f, 0.f};

  const int wave_row = (wid >> 1) * 64;
  const int wave_col = (wid & 1) * 64;

  // staging decomposition
  const int arow  = tid >> 1;        // 0..127
  const int ahalf = tid & 1;         // which 16-wide k half
  const int klocal = tid >> 3;       // 0..31
  const int bj = klocal & 7;
  const int bg = klocal >> 3;
  const int b7 = tid & 7;
  const int bcs = b7 * 16;           // col start
  const int rot = tid & 3;           // chunk rotation to dodge LDS bank conflicts
  const int bbase = (bg * 136 + b7 * 17) * 8 + bj;  // flat bf16 index base

  const int nsteps = K >> 5;
  for (int kt = 0; kt < nsteps; kt++) {
    int k0 = kt << 5;
    // ---- stage A tile (128 x 32 fp32 -> bf16) ----
    {
      const float* ap = Av + (size_t)(bm * 128 + arow) * K + k0 + ahalf * 16;
      float4 q0 = ((const float4*)ap)[0];
      float4 q1 = ((const float4*)ap)[1];
      float4 q2 = ((const float4*)ap)[2];
      float4 q3 = ((const float4*)ap)[3];
      bf16x8 p0, p1;
      p0[0]=(__bf16)q0.x; p0[1]=(__bf16)q0.y; p0[2]=(__bf16)q0.z; p0[3]=(__bf16)q0.w;
      p0[4]=(__bf16)q1.x; p0[5]=(__bf16)q1.y; p0[6]=(__bf16)q1.z; p0[7]=(__bf16)q1.w;
      p1[0]=(__bf16)q2.x; p1[1]=(__bf16)q2.y; p1[2]=(__bf16)q2.z; p1[3]=(__bf16)q2.w;
      p1[4]=(__bf16)q3.x; p1[5]=(__bf16)q3.y; p1[6]=(__bf16)q3.z; p1[7]=(__bf16)q3.w;
      int li = ((arow >> 4) * 17) + (arow & 15);
      Ash[2 * ahalf][li]     = p0;
      Ash[2 * ahalf + 1][li] = p1;
    }
    // ---- stage B tile transposed (32 x 128 fp32 -> bf16, chunk-rotated) ----
    {
      const float* wp = Wv + (size_t)(k0 + klocal) * Nc + bn * 128 + bcs;
      float4 qa = ((const float4*)wp)[(0 + rot) & 3];
      float4 qb = ((const float4*)wp)[(1 + rot) & 3];
      float4 qc = ((const float4*)wp)[(2 + rot) & 3];
      float4 qd = ((const float4*)wp)[(3 + rot) & 3];
#define STB(q, c) { int ch = ((c) + rot) & 3;                      \
      BshS[bbase + (ch * 4 + 0) * 8] = (__bf16)q.x;                \
      BshS[bbase + (ch * 4 + 1) * 8] = (__bf16)q.y;                \
      BshS[bbase + (ch * 4 + 2) * 8] = (__bf16)q.z;                \
      BshS[bbase + (ch * 4 + 3) * 8] = (__bf16)q.w; }
      STB(qa, 0) STB(qb, 1) STB(qc, 2) STB(qd, 3)
#undef STB
    }
    __syncthreads();
    // ---- MFMA ----
    {
      bf16x8 aF[4], bF[4];
      int g = lane >> 4;
      int l15 = lane & 15;
#pragma unroll
      for (int m = 0; m < 4; m++)
        aF[m] = Ash[g][(wave_row / 16 + m) * 17 + l15];
#pragma unroll
      for (int n = 0; n < 4; n++)
        bF[n] = Bsh[g][(wave_col / 16 + n) * 17 + l15];
#pragma unroll
      for (int m = 0; m < 4; m++)
#pragma unroll
        for (int n = 0; n < 4; n++)
          acc[m][n] = __builtin_amdgcn_mfma_f32_16x16x32_bf16(aF[m], bF[n], acc[m][n], 0, 0, 0);
    }
    __syncthreads();
  }

  // ---- epilogue: D row=(lane>>4)*4+q, col=lane&15 ----
#pragma unroll
  for (int m = 0; m < 4; m++) {
    int rbase = bm * 128 + wave_row + m * 16 + (lane >> 4) * 4;
#pragma unroll
    for (int q = 0; q < 4; q++) {
      float* cp = Cv + (size_t)(rbase + q) * Nc + bn * 128 + wave_col + (lane & 15);
#pragma unroll
      for (int n = 0; n < 4; n++) cp[n * 16] = acc[m][n][q];
    }
  }
}

// ---------------------------------------------------------------------------
// CSR SpMM: out[n][f] = sum_e val[e] * in[src[e]][f]   (one block per dst row)
// MODE 0: relu -> out buffer [V][N][F]
// MODE 1: relu -> Z[v][n][0:256]           (c3)
// MODE 2: (h1+h2+acc)/3 -> Z[v][n][256:768] (z_v)
// ---------------------------------------------------------------------------
template <int F, int MODE>
__global__ __launch_bounds__(256) void k_spmm(
    const float* __restrict__ in, const int* __restrict__ rp,
    const int* __restrict__ ssrc, const float* __restrict__ sval,
    float* __restrict__ out, const float* __restrict__ h1, const float* __restrict__ h2)
{
  int n = blockIdx.x, v = blockIdx.y, tid = threadIdx.x;
  constexpr int FPT = F / 256;
  const int* rpv = rp + v * (NN + 1);
  int e = rpv[n], end = rpv[n + 1];
  const int* sv = ssrc + (size_t)v * EE;
  const float* vv = sval + (size_t)v * EE;
  const float* inv = in + (size_t)v * NN * F;

  float acc[FPT];
#pragma unroll
  for (int q = 0; q < FPT; q++) acc[q] = 0.f;

  for (; e + 2 <= end; e += 2) {
    int s0 = sv[e], s1 = sv[e + 1];
    float w0 = vv[e], w1 = vv[e + 1];
    const float* r0 = inv + (size_t)s0 * F;
    const float* r1 = inv + (size_t)s1 * F;
#pragma unroll
    for (int q = 0; q < FPT; q++) acc[q] += w0 * r0[tid + q * 256];
#pragma unroll
    for (int q = 0; q < FPT; q++) acc[q] += w1 * r1[tid + q * 256];
  }
  if (e < end) {
    int s0 = sv[e];
    float w0 = vv[e];
    const float* r0 = inv + (size_t)s0 * F;
#pragma unroll
    for (int q = 0; q < FPT; q++) acc[q] += w0 * r0[tid + q * 256];
  }

  if (MODE == 0) {
    float* o = out + (size_t)v * NN * F + (size_t)n * F;
#pragma unroll
    for (int q = 0; q < FPT; q++) o[tid + q * 256] = fmaxf(acc[q], 0.f);
  } else if (MODE == 1) {
    float* o = out + ((size_t)v * NN + n) * ZF;
#pragma unroll
    for (int q = 0; q < FPT; q++) o[tid + q * 256] = fmaxf(acc[q], 0.f);
  } else {
    const float* hh = h1 + (size_t)v * NN * F + (size_t)n * F;
    const float* mm = h2 + (size_t)v * NN * F + (size_t)n * F;
    float* o = out + ((size_t)v * NN + n) * ZF + CC;
#pragma unroll
    for (int q = 0; q < FPT; q++) {
      int f = tid + q * 256;
      o[f] = (hh[f] + mm[f] + acc[q]) * (1.f / 3.f);
    }
  }
}

// ---------------------------------------------------------------------------
// Gate: per node n, scores[k][i] = <Z[i,n,:], gw[k,i,:]> + gb[k,i];
// softmax over i; z_global[k,n,:] = sum_i p * Z[i,n,:]
// ---------------------------------------------------------------------------
__global__ __launch_bounds__(256) void k_gate(
    const float* __restrict__ Z, const float* __restrict__ gw,
    const float* __restrict__ gb, float* __restrict__ zg)
{
  __shared__ float Zl[NVIEW * ZF];
  __shared__ float sred[36];
  __shared__ float pl[36];
  int n = blockIdx.x, tid = threadIdx.x;

  for (int idx = tid; idx < NVIEW * ZF; idx += 256) {
    int i = idx / ZF, f = idx - i * ZF;
    Zl[idx] = Z[((size_t)i * NN + n) * ZF + f];
  }
  if (tid < 36) sred[tid] = 0.f;
  __syncthreads();

  float acc[36];
#pragma unroll
  for (int p = 0; p < 36; p++) acc[p] = 0.f;
#pragma unroll
  for (int q = 0; q < 3; q++) {
    int f = tid + q * 256;
    float zv[NVIEW];
#pragma unroll
    for (int i = 0; i < NVIEW; i++) zv[i] = Zl[i * ZF + f];
#pragma unroll
    for (int k = 0; k < NVIEW; k++)
#pragma unroll
      for (int i = 0; i < NVIEW; i++)
        acc[k * 6 + i] += zv[i] * gw[(k * 6 + i) * ZF + f];
  }
  int lane = tid & 63;
#pragma unroll
  for (int p = 0; p < 36; p++) {
    float x = acc[p];
    x += __shfl_down(x, 32, 64);
    x += __shfl_down(x, 16, 64);
    x += __shfl_down(x, 8, 64);
    x += __shfl_down(x, 4, 64);
    x += __shfl_down(x, 2, 64);
    x += __shfl_down(x, 1, 64);
    if (lane == 0) atomicAdd(&sred[p], x);
  }
  __syncthreads();

  if (tid < NVIEW) {
    int k = tid;
    float s[NVIEW];
    float mx = -1e30f;
#pragma unroll
    for (int i = 0; i < NVIEW; i++) {
      s[i] = sred[k * 6 + i] + gb[k * 6 + i];
      mx = fmaxf(mx, s[i]);
    }
    float sum = 0.f;
#pragma unroll
    for (int i = 0; i < NVIEW; i++) { s[i] = __expf(s[i] - mx); sum += s[i]; }
    float inv = 1.f / sum;
#pragma unroll
    for (int i = 0; i < NVIEW; i++) pl[k * 6 + i] = s[i] * inv;
  }
  __syncthreads();

#pragma unroll
  for (int q = 0; q < 3; q++) {
    int f = tid + q * 256;
    float zv[NVIEW];
#pragma unroll
    for (int i = 0; i < NVIEW; i++) zv[i] = Zl[i * ZF + f];
#pragma unroll
    for (int k = 0; k < NVIEW; k++) {
      float o = 0.f;
#pragma unroll
      for (int i = 0; i < NVIEW; i++) o += pl[k * 6 + i] * zv[i];
      zg[((size_t)k * NN + n) * ZF + f] = o;
    }
  }
}

// ---------------------------------------------------------------------------
extern "C" void kernel_launch(void* const* d_in, const int* in_sizes, int n_in,
                              void* d_out, int out_size, void* d_ws, size_t ws_size,
                              hipStream_t stream) {
  const float* x    = (const float*)d_in[0];
  const float* aval = (const float*)d_in[1];
  const float* Wb   = (const float*)d_in[2];
  const float* Wo   = (const float*)d_in[3];
  const float* Wf   = (const float*)d_in[4];
  const float* Wc0  = (const float*)d_in[5];
  const float* Wc1  = (const float*)d_in[6];
  const float* Wc2  = (const float*)d_in[7];
  const float* gw   = (const float*)d_in[8];
  const float* gb   = (const float*)d_in[9];
  const int*   asrc = (const int*)d_in[10];
  const int*   adst = (const int*)d_in[11];

  float* zg = (float*)d_out;                       // [6][6400][768]
  float* Z  = zg + (size_t)NVIEW * NN * ZF;        // [6][6400][768]

  char* w = (char*)d_ws;
  auto alloc = [&](size_t bytes) {
    char* p = w;
    w += (bytes + 255) & ~(size_t)255;
    return p;
  };
  int*   hist = (int*)alloc((size_t)NVIEW * NN * 4);          // reused as cursor
  int*   rp   = (int*)alloc((size_t)NVIEW * (NN + 1) * 4);
  int*   ssrc = (int*)alloc((size_t)NVIEW * EE * 4);
  float* sval = (float*)alloc((size_t)NVIEW * EE * 4);
  float* t512 = (float*)alloc((size_t)NVIEW * NN * HH * 4);
  float* hid  = (float*)alloc((size_t)NVIEW * NN * HH * 4);
  float* mid  = (float*)alloc((size_t)NVIEW * NN * HH * 4);
  float* tc   = (float*)alloc((size_t)NVIEW * NN * CC * 4);
  float* cb   = (float*)alloc((size_t)NVIEW * NN * CC * 4);

  // ---- CSR build ----
  (void)hipMemsetAsync(hist, 0, (size_t)NVIEW * NN * 4, stream);
  k_hist<<<dim3(800, NVIEW), 256, 0, stream>>>(adst, hist);
  k_scan<<<NVIEW, 1024, 0, stream>>>(hist, rp);
  k_cursor<<<150, 256, 0, stream>>>(rp, hist);
  k_scatter<<<dim3(800, NVIEW), 256, 0, stream>>>(asrc, adst, aval, hist, ssrc, sval);

  // ---- view-specific path + common path ----
  k_gemm<<<dim3(50, 4, NVIEW), 256, 0, stream>>>(x, Wb, t512, DD, HH, 1);
  k_gemm<<<dim3(50, 2, NVIEW), 256, 0, stream>>>(x, Wc0, tc, DD, CC, 0);
  k_spmm<512, 0><<<dim3(NN, NVIEW), 256, 0, stream>>>(t512, rp, ssrc, sval, hid, nullptr, nullptr);
  k_spmm<256, 0><<<dim3(NN, NVIEW), 256, 0, stream>>>(tc, rp, ssrc, sval, cb, nullptr, nullptr);
  k_gemm<<<dim3(50, 4, NVIEW), 256, 0, stream>>>(hid, Wo, t512, HH, HH, 1);
  k_spmm<512, 0><<<dim3(NN, NVIEW), 256, 0, stream>>>(t512, rp, ssrc, sval, mid, nullptr, nullptr);
  k_gemm<<<dim3(50, 2, NVIEW), 256, 0, stream>>>(cb, Wc1, tc, CC, CC, 0);
  k_spmm<256, 0><<<dim3(NN, NVIEW), 256, 0, stream>>>(tc, rp, ssrc, sval, cb, nullptr, nullptr);
  k_gemm<<<dim3(50, 4, NVIEW), 256, 0, stream>>>(mid, Wf, t512, HH, HH, 1);
  k_spmm<512, 2><<<dim3(NN, NVIEW), 256, 0, stream>>>(t512, rp, ssrc, sval, Z, hid, mid);
  k_gemm<<<dim3(50, 2, NVIEW), 256, 0, stream>>>(cb, Wc2, tc, CC, CC, 0);
  k_spmm<256, 1><<<dim3(NN, NVIEW), 256, 0, stream>>>(tc, rp, ssrc, sval, Z, nullptr, nullptr);

  // ---- gated fusion ----
  k_gate<<<NN, 256, 0, stream>>>(Z, gw, gb, zg);
}

// Round 2
// 1434.735 us; speedup vs baseline: 1.4213x; 1.4213x over previous
//
#include <hip/hip_runtime.h>
#include <hip/hip_bf16.h>

#define NVIEW 6
#define NN    6400
#define DD    2048
#define HH    512
#define CC    256
#define EE    204800
#define ZF    768   // C + H

typedef __bf16 bf16x8 __attribute__((ext_vector_type(8)));
typedef __bf16 bf16x4 __attribute__((ext_vector_type(4)));
typedef float  f32x4  __attribute__((ext_vector_type(4)));

__device__ __forceinline__ float b2f(unsigned short u) {
  union { unsigned int i; float f; } c; c.i = ((unsigned int)u) << 16; return c.f;
}

__device__ __forceinline__ void glds16(const void* g, void* l) {
  __builtin_amdgcn_global_load_lds((const __attribute__((address_space(1))) void*)g,
                                   (__attribute__((address_space(3))) void*)l, 16, 0, 0);
}

// ---------------------------------------------------------------------------
// CSR build
// ---------------------------------------------------------------------------
__global__ void k_hist(const int* __restrict__ dst, int* __restrict__ hist) {
  int e = blockIdx.x * 256 + threadIdx.x;
  int v = blockIdx.y;
  if (e < EE) atomicAdd(&hist[v * NN + dst[(size_t)v * EE + e]], 1);
}

__global__ __launch_bounds__(1024) void k_scan(const int* __restrict__ hist,
                                               int* __restrict__ rp) {
  int v = blockIdx.x;
  const int* h = hist + v * NN;
  int* r = rp + v * (NN + 1);
  __shared__ int part[1024];
  int t = threadIdx.x;
  const int CH = 7;
  int base = t * CH;
  int loc[CH];
  int s = 0;
#pragma unroll
  for (int i = 0; i < CH; i++) {
    int idx = base + i;
    int val = (idx < NN) ? h[idx] : 0;
    loc[i] = s;
    s += val;
  }
  part[t] = s;
  __syncthreads();
  for (int off = 1; off < 1024; off <<= 1) {
    int x = (t >= off) ? part[t - off] : 0;
    __syncthreads();
    part[t] += x;
    __syncthreads();
  }
  int pre = (t == 0) ? 0 : part[t - 1];
#pragma unroll
  for (int i = 0; i < CH; i++) {
    int idx = base + i;
    if (idx < NN) r[idx] = pre + loc[i];
  }
  if (t == 1023) r[NN] = part[1023];
}

__global__ void k_cursor(const int* __restrict__ rp, int* __restrict__ cur) {
  int i = blockIdx.x * 256 + threadIdx.x;
  if (i < NVIEW * NN) {
    int v = i / NN, n = i - v * NN;
    cur[i] = rp[v * (NN + 1) + n];
  }
}

__global__ void k_scatter(const int* __restrict__ src, const int* __restrict__ dstA,
                          const float* __restrict__ val, int* __restrict__ cur,
                          int2* __restrict__ sedge) {
  int e = blockIdx.x * 256 + threadIdx.x;
  int v = blockIdx.y;
  if (e < EE) {
    size_t idx = (size_t)v * EE + e;
    int d = dstA[idx];
    int pos = atomicAdd(&cur[v * NN + d], 1);
    sedge[(size_t)v * EE + pos] = make_int2(src[idx], __float_as_int(val[idx]));
  }
}

// ---------------------------------------------------------------------------
// fp32 -> bf16 copy-convert (x -> xb)
// ---------------------------------------------------------------------------
__global__ __launch_bounds__(256) void k_cvt(const float* __restrict__ in,
                                             __bf16* __restrict__ out) {
  size_t i = (size_t)blockIdx.x * 256 + threadIdx.x;   // float4 index
  float4 q = ((const float4*)in)[i];
  bf16x4 o;
  o[0] = (__bf16)q.x; o[1] = (__bf16)q.y; o[2] = (__bf16)q.z; o[3] = (__bf16)q.w;
  *(bf16x4*)(out + i * 4) = o;
}

// ---------------------------------------------------------------------------
// weight transpose-convert: [B][K][N] fp32 -> [B][N][K] bf16
// ---------------------------------------------------------------------------
__global__ __launch_bounds__(256) void k_tw(const float* __restrict__ in,
                                            __bf16* __restrict__ out, int K, int N) {
  __shared__ float sh[32][33];
  int b = blockIdx.z;
  int k0 = blockIdx.x * 32, n0 = blockIdx.y * 32;
  int tx = threadIdx.x & 31, ty = threadIdx.x >> 5;   // ty 0..7
  const float* I = in + (size_t)b * K * N;
  __bf16* O = out + (size_t)b * K * N;
#pragma unroll
  for (int r = 0; r < 4; r++)
    sh[ty + r * 8][tx] = I[(size_t)(k0 + ty + r * 8) * N + n0 + tx];
  __syncthreads();
#pragma unroll
  for (int r = 0; r < 4; r++)
    O[(size_t)(n0 + ty + r * 8) * K + k0 + tx] = (__bf16)sh[tx][ty + r * 8];
}

// ---------------------------------------------------------------------------
// bf16 MFMA GEMM (m97-style): C[v] = A[v] ([M,K] bf16) * BT ([Nc,K] bf16)^T
// 128x128 tile, BK=32, 4 waves. global_load_lds width=16, LDS chunk layout
// [g(4)][row(128)] of 16B -> bank-balanced ds_read_b128 fragments.
// ---------------------------------------------------------------------------
__global__ __launch_bounds__(256) void k_gemm(
    const __bf16* __restrict__ A, const __bf16* __restrict__ BT,
    __bf16* __restrict__ C, int K, int Nc, int wPerView)
{
  __shared__ __bf16 Alds[4 * 128 * 8];   // chunk c = g*128+row, 8 bf16 per chunk
  __shared__ __bf16 Blds[4 * 128 * 8];
  int tid = threadIdx.x, lane = tid & 63, w = tid >> 6;
  int bm = blockIdx.x, bn = blockIdx.y, v = blockIdx.z;

  const __bf16* Av = A + (size_t)v * NN * K + (size_t)(bm * 128) * K;
  const __bf16* Bv = BT + (wPerView ? (size_t)v * Nc * K : 0) + (size_t)(bn * 128) * K;

  f32x4 acc[4][4];
#pragma unroll
  for (int m = 0; m < 4; m++)
#pragma unroll
    for (int n = 0; n < 4; n++) acc[m][n] = (f32x4){0.f, 0.f, 0.f, 0.f};

  const int wr = (w >> 1) * 64, wc = (w & 1) * 64;
  const int gq = lane >> 4, l15 = lane & 15;

  for (int k0 = 0; k0 < K; k0 += 32) {
    // stage: wave w covers kgroup g=w; lane l, iter i -> row = i*64 + l
#pragma unroll
    for (int i = 0; i < 2; i++) {
      int row = i * 64 + lane;
      glds16(Av + (size_t)row * K + k0 + w * 8, Alds + (w * 128 + i * 64) * 8);
      glds16(Bv + (size_t)row * K + k0 + w * 8, Blds + (w * 128 + i * 64) * 8);
    }
    __syncthreads();
    {
      bf16x8 aF[4], bF[4];
#pragma unroll
      for (int m = 0; m < 4; m++)
        aF[m] = *(const bf16x8*)&Alds[(gq * 128 + wr + m * 16 + l15) * 8];
#pragma unroll
      for (int n = 0; n < 4; n++)
        bF[n] = *(const bf16x8*)&Blds[(gq * 128 + wc + n * 16 + l15) * 8];
#pragma unroll
      for (int m = 0; m < 4; m++)
#pragma unroll
        for (int n = 0; n < 4; n++)
          acc[m][n] = __builtin_amdgcn_mfma_f32_16x16x32_bf16(aF[m], bF[n], acc[m][n], 0, 0, 0);
    }
    __syncthreads();
  }

  // epilogue: D row=(lane>>4)*4+q, col=lane&15 ; write bf16
  __bf16* Cv = C + (size_t)v * NN * Nc;
#pragma unroll
  for (int m = 0; m < 4; m++) {
    int rbase = bm * 128 + wr + m * 16 + (lane >> 4) * 4;
#pragma unroll
    for (int q = 0; q < 4; q++) {
      __bf16* cp = Cv + (size_t)(rbase + q) * Nc + bn * 128 + wc + l15;
#pragma unroll
      for (int n = 0; n < 4; n++) cp[n * 16] = (__bf16)acc[m][n][q];
    }
  }
}

// ---------------------------------------------------------------------------
// CSR SpMM, bf16 gather, 4 rows/block (1 wave each), 256-feature chunks,
// XCD-pinned (view,chunk) for L2 residency.
// MODE 0: relu -> bf16 out [V][N][F]
// MODE 1: relu -> fp32 Z[v][n][0:256]
// MODE 2: (h1+h2+acc)/3 -> fp32 Z[v][n][256:768]
// ---------------------------------------------------------------------------
template <int F, int CHUNKS, int MODE>
__global__ __launch_bounds__(256) void k_spmm(
    const __bf16* __restrict__ in, const int* __restrict__ rp,
    const int2* __restrict__ sedge, void* __restrict__ out,
    const __bf16* __restrict__ h1, const __bf16* __restrict__ h2)
{
  int id = blockIdx.x;
  int s = id & 7, j = id >> 3;
  int ch, v, rowblk;
  if (CHUNKS == 2) {              // XCDs 0-3 -> chunk0, 4-7 -> chunk1
    ch = s >> 2; int q = s & 3;
    v = j / 400; int t = j - v * 400;
    rowblk = t * 4 + q;
  } else {
    ch = 0;
    v = j / 200; int t = j - v * 200;
    rowblk = t * 8 + s;
  }
  int wid = threadIdx.x >> 6, lane = threadIdx.x & 63;
  int n = rowblk * 4 + wid;
  int f0 = ch * 256 + lane * 4;

  const int* rpv = rp + v * (NN + 1);
  int e = rpv[n], end = rpv[n + 1];
  const int2* ev = sedge + (size_t)v * EE;
  const __bf16* inv = in + (size_t)v * NN * F;

  float a0 = 0.f, a1 = 0.f, a2 = 0.f, a3 = 0.f;
  for (; e + 2 <= end; e += 2) {
    int2 e0 = ev[e], e1 = ev[e + 1];
    float w0 = __int_as_float(e0.y), w1 = __int_as_float(e1.y);
    ushort4 r0 = *(const ushort4*)(inv + (size_t)e0.x * F + f0);
    ushort4 r1 = *(const ushort4*)(inv + (size_t)e1.x * F + f0);
    a0 += w0 * b2f(r0.x); a1 += w0 * b2f(r0.y);
    a2 += w0 * b2f(r0.z); a3 += w0 * b2f(r0.w);
    a0 += w1 * b2f(r1.x); a1 += w1 * b2f(r1.y);
    a2 += w1 * b2f(r1.z); a3 += w1 * b2f(r1.w);
  }
  if (e < end) {
    int2 e0 = ev[e];
    float w0 = __int_as_float(e0.y);
    ushort4 r0 = *(const ushort4*)(inv + (size_t)e0.x * F + f0);
    a0 += w0 * b2f(r0.x); a1 += w0 * b2f(r0.y);
    a2 += w0 * b2f(r0.z); a3 += w0 * b2f(r0.w);
  }

  if (MODE == 0) {
    __bf16* o = (__bf16*)out + ((size_t)v * NN + n) * F + f0;
    bf16x4 ov;
    ov[0] = (__bf16)fmaxf(a0, 0.f); ov[1] = (__bf16)fmaxf(a1, 0.f);
    ov[2] = (__bf16)fmaxf(a2, 0.f); ov[3] = (__bf16)fmaxf(a3, 0.f);
    *(bf16x4*)o = ov;
  } else if (MODE == 1) {
    float* o = (float*)out + ((size_t)v * NN + n) * ZF + f0;
    o[0] = fmaxf(a0, 0.f); o[1] = fmaxf(a1, 0.f);
    o[2] = fmaxf(a2, 0.f); o[3] = fmaxf(a3, 0.f);
  } else {
    const __bf16* hh = h1 + ((size_t)v * NN + n) * F + f0;
    const __bf16* mm = h2 + ((size_t)v * NN + n) * F + f0;
    ushort4 hu = *(const ushort4*)hh;
    ushort4 mu = *(const ushort4*)mm;
    float* o = (float*)out + ((size_t)v * NN + n) * ZF + CC + f0;
    o[0] = (b2f(hu.x) + b2f(mu.x) + a0) * (1.f / 3.f);
    o[1] = (b2f(hu.y) + b2f(mu.y) + a1) * (1.f / 3.f);
    o[2] = (b2f(hu.z) + b2f(mu.z) + a2) * (1.f / 3.f);
    o[3] = (b2f(hu.w) + b2f(mu.w) + a3) * (1.f / 3.f);
  }
}

// ---------------------------------------------------------------------------
// Gate
// ---------------------------------------------------------------------------
__global__ __launch_bounds__(256) void k_gate(
    const float* __restrict__ Z, const float* __restrict__ gw,
    const float* __restrict__ gb, float* __restrict__ zg)
{
  __shared__ float Zl[NVIEW * ZF];
  __shared__ float sred[36];
  __shared__ float pl[36];
  int n = blockIdx.x, tid = threadIdx.x;

  for (int idx = tid; idx < NVIEW * ZF; idx += 256) {
    int i = idx / ZF, f = idx - i * ZF;
    Zl[idx] = Z[((size_t)i * NN + n) * ZF + f];
  }
  if (tid < 36) sred[tid] = 0.f;
  __syncthreads();

  float acc[36];
#pragma unroll
  for (int p = 0; p < 36; p++) acc[p] = 0.f;
#pragma unroll
  for (int q = 0; q < 3; q++) {
    int f = tid + q * 256;
    float zv[NVIEW];
#pragma unroll
    for (int i = 0; i < NVIEW; i++) zv[i] = Zl[i * ZF + f];
#pragma unroll
    for (int k = 0; k < NVIEW; k++)
#pragma unroll
      for (int i = 0; i < NVIEW; i++)
        acc[k * 6 + i] += zv[i] * gw[(k * 6 + i) * ZF + f];
  }
  int lane = tid & 63;
#pragma unroll
  for (int p = 0; p < 36; p++) {
    float x = acc[p];
    x += __shfl_down(x, 32, 64);
    x += __shfl_down(x, 16, 64);
    x += __shfl_down(x, 8, 64);
    x += __shfl_down(x, 4, 64);
    x += __shfl_down(x, 2, 64);
    x += __shfl_down(x, 1, 64);
    if (lane == 0) atomicAdd(&sred[p], x);
  }
  __syncthreads();

  if (tid < NVIEW) {
    int k = tid;
    float sc[NVIEW];
    float mx = -1e30f;
#pragma unroll
    for (int i = 0; i < NVIEW; i++) {
      sc[i] = sred[k * 6 + i] + gb[k * 6 + i];
      mx = fmaxf(mx, sc[i]);
    }
    float sum = 0.f;
#pragma unroll
    for (int i = 0; i < NVIEW; i++) { sc[i] = __expf(sc[i] - mx); sum += sc[i]; }
    float inv = 1.f / sum;
#pragma unroll
    for (int i = 0; i < NVIEW; i++) pl[k * 6 + i] = sc[i] * inv;
  }
  __syncthreads();

#pragma unroll
  for (int q = 0; q < 3; q++) {
    int f = tid + q * 256;
    float zv[NVIEW];
#pragma unroll
    for (int i = 0; i < NVIEW; i++) zv[i] = Zl[i * ZF + f];
#pragma unroll
    for (int k = 0; k < NVIEW; k++) {
      float o = 0.f;
#pragma unroll
      for (int i = 0; i < NVIEW; i++) o += pl[k * 6 + i] * zv[i];
      zg[((size_t)k * NN + n) * ZF + f] = o;
    }
  }
}

// ---------------------------------------------------------------------------
extern "C" void kernel_launch(void* const* d_in, const int* in_sizes, int n_in,
                              void* d_out, int out_size, void* d_ws, size_t ws_size,
                              hipStream_t stream) {
  const float* x    = (const float*)d_in[0];
  const float* aval = (const float*)d_in[1];
  const float* Wb   = (const float*)d_in[2];
  const float* Wo   = (const float*)d_in[3];
  const float* Wf   = (const float*)d_in[4];
  const float* Wc0  = (const float*)d_in[5];
  const float* Wc1  = (const float*)d_in[6];
  const float* Wc2  = (const float*)d_in[7];
  const float* gw   = (const float*)d_in[8];
  const float* gb   = (const float*)d_in[9];
  const int*   asrc = (const int*)d_in[10];
  const int*   adst = (const int*)d_in[11];

  float* zg = (float*)d_out;                       // [6][6400][768]
  float* Z  = zg + (size_t)NVIEW * NN * ZF;        // [6][6400][768]
  // xb (157 MB bf16 copy of x) is stashed at the head of d_out: its last read
  // (GEMM #2) precedes the first write to Z (spmm mode2), stream-ordered; zg
  // is written only by the final gate kernel. Fully rewritten every call.
  __bf16* xb = (__bf16*)d_out;

  char* w = (char*)d_ws;
  auto alloc = [&](size_t bytes) {
    char* p = w;
    w += (bytes + 255) & ~(size_t)255;
    return p;
  };
  int*    hist  = (int*)alloc((size_t)NVIEW * NN * 4);          // reused as cursor
  int*    rp    = (int*)alloc((size_t)NVIEW * (NN + 1) * 4);
  int2*   sedge = (int2*)alloc((size_t)NVIEW * EE * 8);
  __bf16* WbT   = (__bf16*)alloc((size_t)NVIEW * HH * DD * 2);
  __bf16* WoT   = (__bf16*)alloc((size_t)NVIEW * HH * HH * 2);
  __bf16* WfT   = (__bf16*)alloc((size_t)NVIEW * HH * HH * 2);
  __bf16* Wc0T  = (__bf16*)alloc((size_t)CC * DD * 2);
  __bf16* Wc1T  = (__bf16*)alloc((size_t)CC * CC * 2);
  __bf16* Wc2T  = (__bf16*)alloc((size_t)CC * CC * 2);
  __bf16* t512b = (__bf16*)alloc((size_t)NVIEW * NN * HH * 2);
  __bf16* hidb  = (__bf16*)alloc((size_t)NVIEW * NN * HH * 2);
  __bf16* midb  = (__bf16*)alloc((size_t)NVIEW * NN * HH * 2);
  __bf16* tcb   = (__bf16*)alloc((size_t)NVIEW * NN * CC * 2);
  __bf16* cbb   = (__bf16*)alloc((size_t)NVIEW * NN * CC * 2);

  // ---- CSR build ----
  (void)hipMemsetAsync(hist, 0, (size_t)NVIEW * NN * 4, stream);
  k_hist<<<dim3(800, NVIEW), 256, 0, stream>>>(adst, hist);
  k_scan<<<NVIEW, 1024, 0, stream>>>(hist, rp);
  k_cursor<<<150, 256, 0, stream>>>(rp, hist);
  k_scatter<<<dim3(800, NVIEW), 256, 0, stream>>>(asrc, adst, aval, hist, sedge);

  // ---- precision/layout prep ----
  k_cvt<<<76800, 256, 0, stream>>>(x, xb);                       // x -> bf16
  k_tw<<<dim3(64, 16, NVIEW), 256, 0, stream>>>(Wb,  WbT,  DD, HH);
  k_tw<<<dim3(16, 16, NVIEW), 256, 0, stream>>>(Wo,  WoT,  HH, HH);
  k_tw<<<dim3(16, 16, NVIEW), 256, 0, stream>>>(Wf,  WfT,  HH, HH);
  k_tw<<<dim3(64,  8, 1),     256, 0, stream>>>(Wc0, Wc0T, DD, CC);
  k_tw<<<dim3( 8,  8, 1),     256, 0, stream>>>(Wc1, Wc1T, CC, CC);
  k_tw<<<dim3( 8,  8, 1),     256, 0, stream>>>(Wc2, Wc2T, CC, CC);

  // ---- view-specific path + common path ----
  k_gemm<<<dim3(50, 4, NVIEW), 256, 0, stream>>>(xb, WbT, t512b, DD, HH, 1);
  k_gemm<<<dim3(50, 2, NVIEW), 256, 0, stream>>>(xb, Wc0T, tcb, DD, CC, 0);
  k_spmm<512, 2, 0><<<19200, 256, 0, stream>>>(t512b, rp, sedge, hidb, nullptr, nullptr);
  k_spmm<256, 1, 0><<<9600, 256, 0, stream>>>(tcb, rp, sedge, cbb, nullptr, nullptr);
  k_gemm<<<dim3(50, 4, NVIEW), 256, 0, stream>>>(hidb, WoT, t512b, HH, HH, 1);
  k_spmm<512, 2, 0><<<19200, 256, 0, stream>>>(t512b, rp, sedge, midb, nullptr, nullptr);
  k_gemm<<<dim3(50, 2, NVIEW), 256, 0, stream>>>(cbb, Wc1T, tcb, CC, CC, 0);
  k_spmm<256, 1, 0><<<9600, 256, 0, stream>>>(tcb, rp, sedge, cbb, nullptr, nullptr);
  k_gemm<<<dim3(50, 4, NVIEW), 256, 0, stream>>>(midb, WfT, t512b, HH, HH, 1);
  k_spmm<512, 2, 2><<<19200, 256, 0, stream>>>(t512b, rp, sedge, Z, hidb, midb);
  k_gemm<<<dim3(50, 2, NVIEW), 256, 0, stream>>>(cbb, Wc2T, tcb, CC, CC, 0);
  k_spmm<256, 1, 1><<<9600, 256, 0, stream>>>(tcb, rp, sedge, Z, nullptr, nullptr);

  // ---- gated fusion ----
  k_gate<<<NN, 256, 0, stream>>>(Z, gw, gb, zg);
}